// Round 10
// baseline (97.629 us; speedup 1.0000x reference)
//
#include <hip/hip_runtime.h>
#include <stdint.h>
#include <math.h>

#define FDIM 126
#define TPB 256

// numpy pairwise_sum for n=126 (n <= PW_BLOCKSIZE=128 branch), bit-exact trees
template <typename F>
__device__ __forceinline__ double pw126d(F a) {
    #pragma clang fp contract(off)
    double r0=a(0), r1=a(1), r2=a(2), r3=a(3), r4=a(4), r5=a(5), r6=a(6), r7=a(7);
    for (int i = 8; i < 120; i += 8) {
        r0 += a(i);   r1 += a(i+1); r2 += a(i+2); r3 += a(i+3);
        r4 += a(i+4); r5 += a(i+5); r6 += a(i+6); r7 += a(i+7);
    }
    double res = ((r0 + r1) + (r2 + r3)) + ((r4 + r5) + (r6 + r7));
    res += a(120); res += a(121); res += a(122); res += a(123); res += a(124); res += a(125);
    return res;
}
template <typename F>
__device__ __forceinline__ float pw126f(F a) {
    #pragma clang fp contract(off)
    float r0=a(0), r1=a(1), r2=a(2), r3=a(3), r4=a(4), r5=a(5), r6=a(6), r7=a(7);
    for (int i = 8; i < 120; i += 8) {
        r0 += a(i);   r1 += a(i+1); r2 += a(i+2); r3 += a(i+3);
        r4 += a(i+4); r5 += a(i+5); r6 += a(i+6); r7 += a(i+7);
    }
    float res = ((r0 + r1) + (r2 + r3)) + ((r4 + r5) + (r6 + r7));
    res += a(120); res += a(121); res += a(122); res += a(123); res += a(124); res += a(125);
    return res;
}

// Mixed-precision np mirror: mu1/var1 in f32 (np.mean keeps dtype), everything
// after "var + 1e-5" (f64 Python literal promotes) in f64.
__global__ __launch_bounds__(TPB) void bnn_v10(
    const float* __restrict__ x,
    const float* __restrict__ conv_w,
    const float* __restrict__ gn1_w, const float* __restrict__ gn1_b,
    const float* __restrict__ gn2_w, const float* __restrict__ gn2_b,
    const float* __restrict__ lin_w, const float* __restrict__ lin_b,
    const float* __restrict__ gn3_w, const float* __restrict__ gn3_b,
    float* __restrict__ out, int nrows)
{
    #pragma clang fp contract(off)
    __shared__ ulonglong2 s_ws[FDIM];   // conv_w row sign bits (f 0-63, 64-125)
    __shared__ ulonglong2 s_wn[FDIM];   // conv_w row nonzero bits
    __shared__ float2 s_g1[FDIM];
    __shared__ float2 s_g2[FDIM];
    __shared__ int8_t s_sl0[128];       // sign(lin_w[0][f])
    __shared__ int8_t s_sl1[128];       // sign(lin_w[1][f])
    __shared__ uint32_t s_h[32][TPB];   // h bytes: dword g = channels 4g..4g+3 of row t
    __shared__ int s_flags;             // 1: w zeros, 2: gn1 nontrivial, 4: gn2 nontrivial

    const int t = threadIdx.x;
    const int64_t row = (int64_t)blockIdx.x * TPB + t;
    const bool rowOK = row < (int64_t)nrows;

    if (t == 0) s_flags = 0;
    __syncthreads();

    // ---- pack conv_w: one thread per output channel (machinery proven v3-v9) ----
    if (t < FDIM) {
        const float* wr = conv_w + t * FDIM;
        uint64_t ws0 = 0, ws1 = 0, wn0 = 0, wn1 = 0;
        for (int f = 0; f < 64; ++f) {
            float v = wr[f];
            ws0 |= (uint64_t)(v < 0.f) << f;
            wn0 |= (uint64_t)(v != 0.f) << f;
        }
        for (int f = 64; f < FDIM; ++f) {
            float v = wr[f];
            ws1 |= (uint64_t)(v < 0.f) << (f - 64);
            wn1 |= (uint64_t)(v != 0.f) << (f - 64);
        }
        s_ws[t] = make_ulonglong2(ws0, ws1);
        s_wn[t] = make_ulonglong2(wn0, wn1);
        if (__popcll(wn0) + __popcll(wn1) != FDIM) atomicOr(&s_flags, 1);

        float g1wv = gn1_w[t], g1bv = gn1_b[t];
        float g2wv = gn2_w[t], g2bv = gn2_b[t];
        s_g1[t] = make_float2(g1wv, g1bv);
        s_g2[t] = make_float2(g2wv, g2bv);
        if (g1wv != 1.f || g1bv != 0.f) atomicOr(&s_flags, 2);
        if (g2wv != 1.f || g2bv != 0.f) atomicOr(&s_flags, 4);

        float l0 = lin_w[t], l1 = lin_w[FDIM + t];
        s_sl0[t] = (int8_t)((l0 > 0.f) - (l0 < 0.f));
        s_sl1[t] = (int8_t)((l1 > 0.f) - (l1 < 0.f));
    }

    // ---- pack own x row: 63 aligned float2 loads ----
    uint64_t xs0 = 0, xs1 = 0, xn0 = 0, xn1 = 0;
    if (rowOK) {
        const float2* xp = (const float2*)(x + row * FDIM);
        for (int k = 0; k < 32; ++k) {
            float2 v = xp[k];
            int b = 2 * k;
            xs0 |= (uint64_t)(v.x < 0.f) << b;
            xs0 |= (uint64_t)(v.y < 0.f) << (b + 1);
            xn0 |= (uint64_t)(v.x != 0.f) << b;
            xn0 |= (uint64_t)(v.y != 0.f) << (b + 1);
        }
        for (int k = 32; k < 63; ++k) {
            float2 v = xp[k];
            int b = 2 * k - 64;
            xs1 |= (uint64_t)(v.x < 0.f) << b;
            xs1 |= (uint64_t)(v.y < 0.f) << (b + 1);
            xn1 |= (uint64_t)(v.x != 0.f) << b;
            xn1 |= (uint64_t)(v.y != 0.f) << (b + 1);
        }
    }
    const int Kx = __popcll(xn0) + __popcll(xn1);
    __syncthreads();
    const int flags = s_flags;

    // ---- h[c] via XOR-popcount (exact integers; np einsum of signs is exact) ----
    int sum = 0;
    if (!(flags & 1)) {
        for (int g = 0; g < 32; ++g) {
            uint32_t pack = 0;
            for (int j = 0; j < 4; ++j) {
                int cc = 4 * g + j;
                if (cc < FDIM) {
                    ulonglong2 w = s_ws[cc];
                    int pc = __popcll((xs0 ^ w.x) & xn0) + __popcll((xs1 ^ w.y) & xn1);
                    int h = Kx - 2 * pc;
                    sum += h;
                    pack |= (uint32_t)(h & 255) << (8 * j);
                }
            }
            s_h[g][t] = pack;
        }
    } else {
        for (int g = 0; g < 32; ++g) {
            uint32_t pack = 0;
            for (int j = 0; j < 4; ++j) {
                int cc = 4 * g + j;
                if (cc < FDIM) {
                    ulonglong2 w = s_ws[cc];
                    ulonglong2 wn = s_wn[cc];
                    uint64_t m0 = xn0 & wn.x, m1 = xn1 & wn.y;
                    int pm = __popcll(m0) + __popcll(m1);
                    int pc = __popcll((xs0 ^ w.x) & m0) + __popcll((xs1 ^ w.y) & m1);
                    int h = pm - 2 * pc;
                    sum += h;
                    pack |= (uint32_t)(h & 255) << (8 * j);
                }
            }
            s_h[g][t] = pack;
        }
    }

    auto hget = [&](int i) -> int {
        return (int)(int8_t)((s_h[i >> 2][t] >> ((i & 3) << 3)) & 255u);
    };

    // ---- GN1 stats in FLOAT32 (np.mean keeps f32), pairwise trees ----
    const float mu1f = (float)sum / 126.0f;          // pairwise f32 sum of ints is exact
    const float var1f = pw126f([&](int i) -> float {
        #pragma clang fp contract(off)
        float e = (float)hget(i) - mu1f;             // the f32 (h - mu) array
        return e * e;
    }) / 126.0f;
    // var1(f32) + 1e-5 (f64 literal) promotes -> f64 from here on
    const double r1 = 1.0 / sqrt((double)var1f + 1e-5);

    int ip0 = 0, ip1 = 0;   // exact integer dots sum hb*sign(lin_w[c])
    if (!(flags & 6)) {
        // gamma=1, beta=0: y*1+0 bit-identity; sign((c1-mu2)*r2) == sign(c1-mu2)
        auto c1f = [&](int i) -> double {
            #pragma clang fp contract(off)
            float e32 = (float)hget(i) - mu1f;       // f32 element of (h - mu)
            double y = (double)e32 * r1;             // promoted multiply in f64
            return fmin(fmax(y, -1.0), 1.0);
        };
        const double mu2 = pw126d(c1f) / 126.0;
        for (int c = 0; c < FDIM; ++c) {
            double z = c1f(c) - mu2;
            int hb = (z > 0.0) - (z < 0.0);
            ip0 += hb * (int)s_sl0[c];
            ip1 += hb * (int)s_sl1[c];
        }
    } else {
        auto c1f = [&](int i) -> double {
            #pragma clang fp contract(off)
            float e32 = (float)hget(i) - mu1f;
            float2 g = s_g1[i];
            double y = (((double)e32 * r1) * (double)g.x) + (double)g.y;
            return fmin(fmax(y, -1.0), 1.0);
        };
        const double mu2 = pw126d(c1f) / 126.0;
        const double var2 = pw126d([&](int i) -> double {
            #pragma clang fp contract(off)
            double e2 = c1f(i) - mu2;
            return e2 * e2;
        }) / 126.0;
        const double r2 = 1.0 / sqrt(var2 + 1e-5);
        for (int c = 0; c < FDIM; ++c) {
            double e2 = c1f(c) - mu2;
            float2 g2 = s_g2[c];
            double z = ((e2 * r2) * (double)g2.x) + (double)g2.y;  // clip preserves sign
            int hb = (z > 0.0) - (z < 0.0);
            ip0 += hb * (int)s_sl0[c];
            ip1 += hb * (int)s_sl1[c];
        }
    }

    // ---- BNNLinear + GN3 in f64 (bf16/f32 cast makes rounding non-critical) ----
    if (rowOK) {
        double o0 = (double)ip0 + (double)lin_b[0];
        double o1 = (double)ip1 + (double)lin_b[1];
        double mu = (o0 + o1) / 2.0;
        double d0 = o0 - mu, d1 = o1 - mu;
        double var = ((d0 * d0) + (d1 * d1)) / 2.0;
        double r3 = 1.0 / sqrt(var + 1e-5);
        double q0 = ((d0 * r3) * (double)gn3_w[0]) + (double)gn3_b[0];
        double q1 = ((d1 * r3) * (double)gn3_w[1]) + (double)gn3_b[1];
        reinterpret_cast<float2*>(out)[row] = make_float2((float)q0, (float)q1);
    }
}

extern "C" void kernel_launch(void* const* d_in, const int* in_sizes, int n_in,
                              void* d_out, int out_size, void* d_ws, size_t ws_size,
                              hipStream_t stream) {
    const float* x      = (const float*)d_in[0];
    const float* conv_w = (const float*)d_in[1];
    const float* gn1_w  = (const float*)d_in[2];
    const float* gn1_b  = (const float*)d_in[3];
    const float* gn2_w  = (const float*)d_in[4];
    const float* gn2_b  = (const float*)d_in[5];
    const float* lin_w  = (const float*)d_in[6];
    const float* lin_b  = (const float*)d_in[7];
    const float* gn3_w  = (const float*)d_in[8];
    const float* gn3_b  = (const float*)d_in[9];

    int nrows = in_sizes[0] / FDIM;
    int nblocks = (nrows + TPB - 1) / TPB;
    bnn_v10<<<nblocks, TPB, 0, stream>>>(x, conv_w, gn1_w, gn1_b, gn2_w, gn2_b,
                                         lin_w, lin_b, gn3_w, gn3_b,
                                         (float*)d_out, nrows);
}

// Round 11
// 97.525 us; speedup vs baseline: 1.0011x; 1.0011x over previous
//
#include <hip/hip_runtime.h>
#include <stdint.h>
#include <math.h>

#define FDIM 126
#define TPB 256

// numpy pairwise_sum for n=126 (n <= PW_BLOCKSIZE=128 branch), bit-exact trees
template <typename F>
__device__ __forceinline__ double pw126d(F a) {
    #pragma clang fp contract(off)
    double r0=a(0), r1=a(1), r2=a(2), r3=a(3), r4=a(4), r5=a(5), r6=a(6), r7=a(7);
    for (int i = 8; i < 120; i += 8) {
        r0 += a(i);   r1 += a(i+1); r2 += a(i+2); r3 += a(i+3);
        r4 += a(i+4); r5 += a(i+5); r6 += a(i+6); r7 += a(i+7);
    }
    double res = ((r0 + r1) + (r2 + r3)) + ((r4 + r5) + (r6 + r7));
    res += a(120); res += a(121); res += a(122); res += a(123); res += a(124); res += a(125);
    return res;
}
template <typename F>
__device__ __forceinline__ float pw126f(F a) {
    #pragma clang fp contract(off)
    float r0=a(0), r1=a(1), r2=a(2), r3=a(3), r4=a(4), r5=a(5), r6=a(6), r7=a(7);
    for (int i = 8; i < 120; i += 8) {
        r0 += a(i);   r1 += a(i+1); r2 += a(i+2); r3 += a(i+3);
        r4 += a(i+4); r5 += a(i+5); r6 += a(i+6); r7 += a(i+7);
    }
    float res = ((r0 + r1) + (r2 + r3)) + ((r4 + r5) + (r6 + r7));
    res += a(120); res += a(121); res += a(122); res += a(123); res += a(124); res += a(125);
    return res;
}

// Mixed-precision np mirror: mu1/var1 in f32 (np.mean keeps dtype), everything
// after "var + 1e-5" (f64 Python literal promotes) in f64.
__global__ __launch_bounds__(TPB) void bnn_v10(
    const float* __restrict__ x,
    const float* __restrict__ conv_w,
    const float* __restrict__ gn1_w, const float* __restrict__ gn1_b,
    const float* __restrict__ gn2_w, const float* __restrict__ gn2_b,
    const float* __restrict__ lin_w, const float* __restrict__ lin_b,
    const float* __restrict__ gn3_w, const float* __restrict__ gn3_b,
    float* __restrict__ out, int nrows)
{
    #pragma clang fp contract(off)
    __shared__ ulonglong2 s_ws[FDIM];   // conv_w row sign bits (f 0-63, 64-125)
    __shared__ ulonglong2 s_wn[FDIM];   // conv_w row nonzero bits
    __shared__ float2 s_g1[FDIM];
    __shared__ float2 s_g2[FDIM];
    __shared__ int8_t s_sl0[128];       // sign(lin_w[0][f])
    __shared__ int8_t s_sl1[128];       // sign(lin_w[1][f])
    __shared__ uint32_t s_h[32][TPB];   // h bytes: dword g = channels 4g..4g+3 of row t
    __shared__ int s_flags;             // 1: w zeros, 2: gn1 nontrivial, 4: gn2 nontrivial

    const int t = threadIdx.x;
    const int64_t row = (int64_t)blockIdx.x * TPB + t;
    const bool rowOK = row < (int64_t)nrows;

    if (t == 0) s_flags = 0;
    __syncthreads();

    // ---- pack conv_w: one thread per output channel (machinery proven v3-v9) ----
    if (t < FDIM) {
        const float* wr = conv_w + t * FDIM;
        uint64_t ws0 = 0, ws1 = 0, wn0 = 0, wn1 = 0;
        for (int f = 0; f < 64; ++f) {
            float v = wr[f];
            ws0 |= (uint64_t)(v < 0.f) << f;
            wn0 |= (uint64_t)(v != 0.f) << f;
        }
        for (int f = 64; f < FDIM; ++f) {
            float v = wr[f];
            ws1 |= (uint64_t)(v < 0.f) << (f - 64);
            wn1 |= (uint64_t)(v != 0.f) << (f - 64);
        }
        s_ws[t] = make_ulonglong2(ws0, ws1);
        s_wn[t] = make_ulonglong2(wn0, wn1);
        if (__popcll(wn0) + __popcll(wn1) != FDIM) atomicOr(&s_flags, 1);

        float g1wv = gn1_w[t], g1bv = gn1_b[t];
        float g2wv = gn2_w[t], g2bv = gn2_b[t];
        s_g1[t] = make_float2(g1wv, g1bv);
        s_g2[t] = make_float2(g2wv, g2bv);
        if (g1wv != 1.f || g1bv != 0.f) atomicOr(&s_flags, 2);
        if (g2wv != 1.f || g2bv != 0.f) atomicOr(&s_flags, 4);

        float l0 = lin_w[t], l1 = lin_w[FDIM + t];
        s_sl0[t] = (int8_t)((l0 > 0.f) - (l0 < 0.f));
        s_sl1[t] = (int8_t)((l1 > 0.f) - (l1 < 0.f));
    }

    // ---- pack own x row: 63 aligned float2 loads ----
    uint64_t xs0 = 0, xs1 = 0, xn0 = 0, xn1 = 0;
    if (rowOK) {
        const float2* xp = (const float2*)(x + row * FDIM);
        for (int k = 0; k < 32; ++k) {
            float2 v = xp[k];
            int b = 2 * k;
            xs0 |= (uint64_t)(v.x < 0.f) << b;
            xs0 |= (uint64_t)(v.y < 0.f) << (b + 1);
            xn0 |= (uint64_t)(v.x != 0.f) << b;
            xn0 |= (uint64_t)(v.y != 0.f) << (b + 1);
        }
        for (int k = 32; k < 63; ++k) {
            float2 v = xp[k];
            int b = 2 * k - 64;
            xs1 |= (uint64_t)(v.x < 0.f) << b;
            xs1 |= (uint64_t)(v.y < 0.f) << (b + 1);
            xn1 |= (uint64_t)(v.x != 0.f) << b;
            xn1 |= (uint64_t)(v.y != 0.f) << (b + 1);
        }
    }
    const int Kx = __popcll(xn0) + __popcll(xn1);
    __syncthreads();
    const int flags = s_flags;

    // ---- h[c] via XOR-popcount (exact integers; np einsum of signs is exact) ----
    int sum = 0;
    if (!(flags & 1)) {
        for (int g = 0; g < 32; ++g) {
            uint32_t pack = 0;
            for (int j = 0; j < 4; ++j) {
                int cc = 4 * g + j;
                if (cc < FDIM) {
                    ulonglong2 w = s_ws[cc];
                    int pc = __popcll((xs0 ^ w.x) & xn0) + __popcll((xs1 ^ w.y) & xn1);
                    int h = Kx - 2 * pc;
                    sum += h;
                    pack |= (uint32_t)(h & 255) << (8 * j);
                }
            }
            s_h[g][t] = pack;
        }
    } else {
        for (int g = 0; g < 32; ++g) {
            uint32_t pack = 0;
            for (int j = 0; j < 4; ++j) {
                int cc = 4 * g + j;
                if (cc < FDIM) {
                    ulonglong2 w = s_ws[cc];
                    ulonglong2 wn = s_wn[cc];
                    uint64_t m0 = xn0 & wn.x, m1 = xn1 & wn.y;
                    int pm = __popcll(m0) + __popcll(m1);
                    int pc = __popcll((xs0 ^ w.x) & m0) + __popcll((xs1 ^ w.y) & m1);
                    int h = pm - 2 * pc;
                    sum += h;
                    pack |= (uint32_t)(h & 255) << (8 * j);
                }
            }
            s_h[g][t] = pack;
        }
    }

    auto hget = [&](int i) -> int {
        return (int)(int8_t)((s_h[i >> 2][t] >> ((i & 3) << 3)) & 255u);
    };

    // ---- GN1 stats in FLOAT32 (np.mean keeps f32), pairwise trees ----
    const float mu1f = (float)sum / 126.0f;          // pairwise f32 sum of ints is exact
    const float var1f = pw126f([&](int i) -> float {
        #pragma clang fp contract(off)
        float e = (float)hget(i) - mu1f;             // the f32 (h - mu) array
        return e * e;
    }) / 126.0f;
    // var1(f32) + 1e-5 (f64 literal) promotes -> f64 from here on
    const double r1 = 1.0 / sqrt((double)var1f + 1e-5);

    int ip0 = 0, ip1 = 0;   // exact integer dots sum hb*sign(lin_w[c])
    if (!(flags & 6)) {
        // gamma=1, beta=0: y*1+0 bit-identity; sign((c1-mu2)*r2) == sign(c1-mu2)
        auto c1f = [&](int i) -> double {
            #pragma clang fp contract(off)
            float e32 = (float)hget(i) - mu1f;       // f32 element of (h - mu)
            double y = (double)e32 * r1;             // promoted multiply in f64
            return fmin(fmax(y, -1.0), 1.0);
        };
        const double mu2 = pw126d(c1f) / 126.0;
        for (int c = 0; c < FDIM; ++c) {
            double z = c1f(c) - mu2;
            int hb = (z > 0.0) - (z < 0.0);
            ip0 += hb * (int)s_sl0[c];
            ip1 += hb * (int)s_sl1[c];
        }
    } else {
        auto c1f = [&](int i) -> double {
            #pragma clang fp contract(off)
            float e32 = (float)hget(i) - mu1f;
            float2 g = s_g1[i];
            double y = (((double)e32 * r1) * (double)g.x) + (double)g.y;
            return fmin(fmax(y, -1.0), 1.0);
        };
        const double mu2 = pw126d(c1f) / 126.0;
        const double var2 = pw126d([&](int i) -> double {
            #pragma clang fp contract(off)
            double e2 = c1f(i) - mu2;
            return e2 * e2;
        }) / 126.0;
        const double r2 = 1.0 / sqrt(var2 + 1e-5);
        for (int c = 0; c < FDIM; ++c) {
            double e2 = c1f(c) - mu2;
            float2 g2 = s_g2[c];
            double z = ((e2 * r2) * (double)g2.x) + (double)g2.y;  // clip preserves sign
            int hb = (z > 0.0) - (z < 0.0);
            ip0 += hb * (int)s_sl0[c];
            ip1 += hb * (int)s_sl1[c];
        }
    }

    // ---- BNNLinear + GN3 in f64 (bf16/f32 cast makes rounding non-critical) ----
    if (rowOK) {
        double o0 = (double)ip0 + (double)lin_b[0];
        double o1 = (double)ip1 + (double)lin_b[1];
        double mu = (o0 + o1) / 2.0;
        double d0 = o0 - mu, d1 = o1 - mu;
        double var = ((d0 * d0) + (d1 * d1)) / 2.0;
        double r3 = 1.0 / sqrt(var + 1e-5);
        double q0 = ((d0 * r3) * (double)gn3_w[0]) + (double)gn3_b[0];
        double q1 = ((d1 * r3) * (double)gn3_w[1]) + (double)gn3_b[1];
        reinterpret_cast<float2*>(out)[row] = make_float2((float)q0, (float)q1);
    }
}

extern "C" void kernel_launch(void* const* d_in, const int* in_sizes, int n_in,
                              void* d_out, int out_size, void* d_ws, size_t ws_size,
                              hipStream_t stream) {
    const float* x      = (const float*)d_in[0];
    const float* conv_w = (const float*)d_in[1];
    const float* gn1_w  = (const float*)d_in[2];
    const float* gn1_b  = (const float*)d_in[3];
    const float* gn2_w  = (const float*)d_in[4];
    const float* gn2_b  = (const float*)d_in[5];
    const float* lin_w  = (const float*)d_in[6];
    const float* lin_b  = (const float*)d_in[7];
    const float* gn3_w  = (const float*)d_in[8];
    const float* gn3_b  = (const float*)d_in[9];

    int nrows = in_sizes[0] / FDIM;
    int nblocks = (nrows + TPB - 1) / TPB;
    bnn_v10<<<nblocks, TPB, 0, stream>>>(x, conv_w, gn1_w, gn1_b, gn2_w, gn2_b,
                                         lin_w, lin_b, gn3_w, gn3_b,
                                         (float*)d_out, nrows);
}